// Round 17
// baseline (208.977 us; speedup 1.0000x reference)
//
#include <hip/hip_runtime.h>
#include <hip/hip_bf16.h>

#define N_NODES 4096
#define C_CH    8
#define IN_DIM  256
#define D_DIM   64
#define CD      512
#define OUT_DIM 128
#define ITERS   4
#define STRIDE  128     // max degree slack (mean 41, sd 6.4; 128 is >13 sigma)

typedef __hip_bfloat16 bf16;
typedef short short8 __attribute__((ext_vector_type(8)));
typedef float floatx4 __attribute__((ext_vector_type(4)));
typedef unsigned uintx4 __attribute__((ext_vector_type(4)));   // clang vector for NT store

__device__ __forceinline__ float bf2f(bf16 x) { return __bfloat162float(x); }

__device__ __forceinline__ unsigned f2b_rne(float x) {
    unsigned u = __float_as_uint(x);
    return (u + 0x7FFFu + ((u >> 16) & 1u)) >> 16;
}
__device__ __forceinline__ unsigned pack2bf(float a, float b) {
    return f2b_rne(a) | (f2b_rne(b) << 16);
}
__device__ __forceinline__ void unpack2(unsigned v, float& a, float& b) {
    a = __uint_as_float(v << 16);
    b = __uint_as_float(v & 0xFFFF0000u);
}
__device__ __forceinline__ short8 as_s8(uint4 u) {
    union { uint4 a; short8 b; } x; x.a = u; return x.b;
}

// VALU-pipe butterfly step: x + dpp_move(x). No DS unit involvement.
// CTRL: 0xB1 = quad_perm(1,0,3,2) -> xor1 ; 0x4E = quad_perm(2,3,0,1) -> xor2
//       0x141 = row_half_mirror -> quad swap within 8 ; 0x128 = row_ror:8
template<int CTRL>
__device__ __forceinline__ float dpp_add(float x) {
    int yi = __builtin_amdgcn_update_dpp(0, __float_as_int(x), CTRL, 0xF, 0xF, true);
    return x + __int_as_float(yi);
}

// Per-wave dtype detect from first 64 dwords of features.
__device__ __forceinline__ bool wave_detect(const unsigned* __restrict__ feat_u) {
    int lane = threadIdx.x & 63;
    unsigned u = feat_u[lane];
    int e = (u >> 7) & 0xFF;
    int vote = (e >= 0x68 && e <= 0x86) ? 1 : 0;
    #pragma unroll
    for (int off = 32; off; off >>= 1) vote += __shfl_xor(vote, off);
    return vote >= 32;
}

// ---------------------------------------------------------------------------
// Stage A: blocks [0,8) -> Wt[col][k] bf16 (LDS-tiled transpose of W);
//          blocks [8,72) -> Wo_t[n][k] bf16.
// ---------------------------------------------------------------------------
__global__ __launch_bounds__(256) void stage_a(
        const void* __restrict__ feat, const void* __restrict__ W,
        const void* __restrict__ Wo,
        unsigned short* __restrict__ Wt, unsigned short* __restrict__ Wo_t) {
    bool isbf = wave_detect((const unsigned*)feat);
    int bx = blockIdx.x, t = threadIdx.x;
    if (bx < 8) {
        __shared__ __align__(16) unsigned short lt[IN_DIM * D_DIM];   // 32 KB [k][d]
        int c = bx;
        if (isbf) {
            const uint4* p = (const uint4*)((const unsigned short*)W + (size_t)c * IN_DIM * D_DIM);
            #pragma unroll
            for (int i = 0; i < 8; i++) {
                int idx = t + i * 256;
                *(uint4*)&lt[idx * 8] = p[idx];
            }
        } else {
            const float4* p = (const float4*)((const float*)W + (size_t)c * IN_DIM * D_DIM);
            #pragma unroll
            for (int i = 0; i < 16; i++) {
                int idx = t + i * 256;
                float4 f = p[idx];
                uint2 v = make_uint2(pack2bf(f.x, f.y), pack2bf(f.z, f.w));
                *(uint2*)&lt[idx * 4] = v;
            }
        }
        __syncthreads();
        uint4* wt4 = (uint4*)Wt;
        #pragma unroll
        for (int i = 0; i < 8; i++) {
            int j = t + i * 256;
            int d = j >> 5, seg = j & 31;
            int k0 = seg * 8;
            unsigned short v[8];
            #pragma unroll
            for (int k = 0; k < 8; k++) v[k] = lt[(k0 + k) * D_DIM + d];
            uint4 o;
            o.x = v[0] | ((unsigned)v[1] << 16);
            o.y = v[2] | ((unsigned)v[3] << 16);
            o.z = v[4] | ((unsigned)v[5] << 16);
            o.w = v[6] | ((unsigned)v[7] << 16);
            wt4[(c * 64 + d) * 32 + seg] = o;
        }
    } else {
        int base = (bx - 8) * 1024 + t * 4;
        #pragma unroll
        for (int q = 0; q < 4; q++) {
            int idx = base + q;
            int k = idx >> 7, n = idx & 127;
            unsigned short v;
            if (isbf) v = ((const unsigned short*)Wo)[idx];
            else      v = (unsigned short)f2b_rne(((const float*)Wo)[idx]);
            Wo_t[n * CD + k] = v;
        }
    }
}

// ---------------------------------------------------------------------------
// Stage B: blocks [0,256) -> MFMA projection (16 rows x 512 cols per block,
// wave w covers cols w*128.. = channels 2w,2w+1); blocks [256,1280) -> build.
// C/D layout: col=lane&15, row=quad*4+reg (HW-verified).
// ---------------------------------------------------------------------------
__global__ __launch_bounds__(256) void stage_b(
        const void* __restrict__ feat, const void* __restrict__ adj,
        const void* __restrict__ b, const unsigned short* __restrict__ Wt,
        unsigned* __restrict__ zbf, int* __restrict__ deg,
        int* __restrict__ col_buf) {
    bool isbf = wave_detect((const unsigned*)feat);
    int bx = blockIdx.x, t = threadIdx.x;
    int w = t >> 6, lane = t & 63;
    __shared__ __align__(16) unsigned short zt[16 * CD];   // 16 KB

    if (bx < 256) {
        int r0 = bx * 16;
        int n0 = w * 128;
        int m = lane & 15, quad = lane >> 4;
        int row = r0 + m;
        floatx4 acc[8];
        #pragma unroll
        for (int j = 0; j < 8; j++) acc[j] = (floatx4){0.f, 0.f, 0.f, 0.f};
        const uint4* wt4 = (const uint4*)Wt;

        if (isbf) {
            const uint4* a4 = (const uint4*)feat + (size_t)row * 32 + quad;
            #pragma unroll
            for (int k0 = 0; k0 < 8; k0++) {
                short8 a = as_s8(a4[k0 * 4]);
                #pragma unroll
                for (int j = 0; j < 8; j++) {
                    int col = n0 + j * 16 + m;
                    short8 bb = as_s8(wt4[col * 32 + k0 * 4 + quad]);
                    acc[j] = __builtin_amdgcn_mfma_f32_16x16x32_bf16(a, bb, acc[j], 0, 0, 0);
                }
            }
        } else {
            const float4* a4 = (const float4*)feat + (size_t)row * 64 + quad * 2;
            #pragma unroll
            for (int k0 = 0; k0 < 8; k0++) {
                float4 f0 = a4[k0 * 8], f1 = a4[k0 * 8 + 1];
                uint4 au;
                au.x = pack2bf(f0.x, f0.y); au.y = pack2bf(f0.z, f0.w);
                au.z = pack2bf(f1.x, f1.y); au.w = pack2bf(f1.z, f1.w);
                short8 a = as_s8(au);
                #pragma unroll
                for (int j = 0; j < 8; j++) {
                    int col = n0 + j * 16 + m;
                    short8 bb = as_s8(wt4[col * 32 + k0 * 4 + quad]);
                    acc[j] = __builtin_amdgcn_mfma_f32_16x16x32_bf16(a, bb, acc[j], 0, 0, 0);
                }
            }
        }

        float pre[8][4];
        #pragma unroll
        for (int j = 0; j < 8; j++) {
            int col = n0 + j * 16 + m;
            float bb = isbf ? bf2f(((const bf16*)b)[col]) : ((const float*)b)[col];
            #pragma unroll
            for (int r = 0; r < 4; r++) pre[j][r] = acc[j][r] + bb;
        }
        #pragma unroll
        for (int ch = 0; ch < 2; ch++) {
            float ss[4];
            #pragma unroll
            for (int r = 0; r < 4; r++) {
                float s = 0.f;
                #pragma unroll
                for (int jj = 0; jj < 4; jj++) {
                    float v = pre[ch * 4 + jj][r];
                    s = fmaf(v, v, s);
                }
                ss[r] = s;
            }
            #pragma unroll
            for (int off = 1; off < 16; off <<= 1) {
                #pragma unroll
                for (int r = 0; r < 4; r++) ss[r] += __shfl_xor(ss[r], off);
            }
            #pragma unroll
            for (int r = 0; r < 4; r++) {
                float sc = __builtin_amdgcn_rsqf(fmaxf(ss[r], 1e-12f));
                int lrow = quad * 4 + r;
                #pragma unroll
                for (int jj = 0; jj < 4; jj++) {
                    int j = ch * 4 + jj;
                    int col = n0 + j * 16 + m;
                    zt[lrow * CD + col] = (unsigned short)f2b_rne(pre[j][r] * sc);
                }
            }
        }
        __syncthreads();
        const uint4* zt4 = (const uint4*)zt;
        uint4* z4 = (uint4*)zbf;
        #pragma unroll
        for (int i = 0; i < 4; i++) {
            int j = t + i * 256;
            int lrow = j >> 6, seg = j & 63;
            z4[(size_t)(r0 + lrow) * 64 + seg] = zt4[j];
        }
    } else {
        // ----- build: one wave per adjacency row, shfl scan
        int i = (bx - 256) * 4 + w;
        int base_out = i * STRIDE;
        int running = 0;
        int nch = isbf ? 8 : 16;
        for (int ch = 0; ch < nch; ch++) {
            unsigned bits = 0;
            int j0, nelem;
            if (isbf) {
                const uint4* p = (const uint4*)((const unsigned short*)adj + (size_t)i * N_NODES);
                uint4 u = p[ch * 64 + lane];
                j0 = (ch * 64 + lane) * 8; nelem = 8;
                unsigned short h[8] = {
                    (unsigned short)(u.x & 0xFFFF), (unsigned short)(u.x >> 16),
                    (unsigned short)(u.y & 0xFFFF), (unsigned short)(u.y >> 16),
                    (unsigned short)(u.z & 0xFFFF), (unsigned short)(u.z >> 16),
                    (unsigned short)(u.w & 0xFFFF), (unsigned short)(u.w >> 16)};
                #pragma unroll
                for (int k = 0; k < 8; k++)
                    if ((h[k] & 0x8000) == 0 && h[k] != 0) bits |= (1u << k);
            } else {
                const float4* p = (const float4*)((const float*)adj + (size_t)i * N_NODES);
                float4 f = p[ch * 64 + lane];
                j0 = (ch * 64 + lane) * 4; nelem = 4;
                if (f.x > 0.f) bits |= 1u;
                if (f.y > 0.f) bits |= 2u;
                if (f.z > 0.f) bits |= 4u;
                if (f.w > 0.f) bits |= 8u;
            }
            int cnt = __popc(bits);
            int sc = cnt;
            #pragma unroll
            for (int off = 1; off < 64; off <<= 1) {
                int v = __shfl_up(sc, off);
                if (lane >= off) sc += v;
            }
            int tot = __shfl(sc, 63);
            int pos = base_out + running + (sc - cnt);
            for (int k = 0; k < nelem; k++) {
                if ((bits >> k) & 1u) {
                    if (pos < base_out + STRIDE) col_buf[pos] = j0 + k;
                    pos++;
                }
            }
            running += tot;
        }
        if (lane == 0) deg[i] = (running < STRIDE) ? running : STRIDE;
    }
}

// ---------------------------------------------------------------------------
// Routing iteration: ONE node per block, edge list split across 4 waves,
// partials combined in LDS. Per-edge cross-lane work now 100% off the DS
// unit: 8-lane dot = 3 DPP adds; channel sum = row_ror:8 DPP + v_readlane
// x4 (VALU pipe). zbf_out written NON-TEMPORAL so the streamed output does
// not evict the gather-hot zbf_in (4 MB) from the 4 MB per-XCD L2.
// Lane: g = lane>>3 (channel), s = lane&7 (dim octet).
// ---------------------------------------------------------------------------
__device__ __forceinline__ void edge_step(const float zi[8], float acc[8], uint4 u) {
    float vj[8];
    unpack2(u.x, vj[0], vj[1]);
    unpack2(u.y, vj[2], vj[3]);
    unpack2(u.z, vj[4], vj[5]);
    unpack2(u.w, vj[6], vj[7]);
    float p = 0.f;
    #pragma unroll
    for (int k = 0; k < 8; k++) p = fmaf(zi[k], vj[k], p);
    // reduce over s (8 lanes) entirely on the VALU pipe
    p = dpp_add<0xB1>(p);      // xor1
    p = dpp_add<0x4E>(p);      // xor2
    p = dpp_add<0x141>(p);     // quad swap within 8
    float ex = __expf(p);      // |p| <= 1 (unit vectors): shift-free softmax
    // channel sum: stride 8 on DPP; strides 16/32 via readlane (VALU, no DS)
    float s2 = dpp_add<0x128>(ex);      // row_ror:8 -> row-uniform pair sum
    int s2i = __float_as_int(s2);
    float r0 = __int_as_float(__builtin_amdgcn_readlane(s2i, 0));
    float r1 = __int_as_float(__builtin_amdgcn_readlane(s2i, 16));
    float r2 = __int_as_float(__builtin_amdgcn_readlane(s2i, 32));
    float r3 = __int_as_float(__builtin_amdgcn_readlane(s2i, 48));
    float s = (r0 + r1) + (r2 + r3);
    float wgt = ex * __builtin_amdgcn_rcpf(s);
    #pragma unroll
    for (int k = 0; k < 8; k++) acc[k] = fmaf(wgt, vj[k], acc[k]);
}

__global__ __launch_bounds__(256) void route_kernel(
        const unsigned* __restrict__ zbf_in, unsigned* __restrict__ zbf_out,
        const int* __restrict__ deg, const int* __restrict__ col_buf) {
    int t = threadIdx.x;
    int w = t >> 6, lane = t & 63;
    int i = blockIdx.x;
    int g = lane >> 3, s = lane & 7;
    __shared__ int   s_cols[STRIDE];
    __shared__ float s_acc[3][CD];
    if (t < STRIDE) s_cols[t] = col_buf[i * STRIDE + t];
    __syncthreads();

    int frag = g * 32 + s * 4;
    uint4 uown = *(const uint4*)(zbf_in + (size_t)i * 256 + frag);
    float zi[8], acc[8];
    unpack2(uown.x, zi[0], zi[1]); unpack2(uown.y, zi[2], zi[3]);
    unpack2(uown.z, zi[4], zi[5]); unpack2(uown.w, zi[6], zi[7]);
    #pragma unroll
    for (int k = 0; k < 8; k++) acc[k] = (w == 0) ? zi[k] : 0.f;  // residual once

    int dg = deg[i];
    int e   = (dg * w) >> 2;
    int end = (dg * (w + 1)) >> 2;
    for (; e + 3 < end; e += 4) {
        int j0 = s_cols[e]     & (N_NODES - 1);
        int j1 = s_cols[e + 1] & (N_NODES - 1);
        int j2 = s_cols[e + 2] & (N_NODES - 1);
        int j3 = s_cols[e + 3] & (N_NODES - 1);
        uint4 u0 = *(const uint4*)(zbf_in + (size_t)j0 * 256 + frag);
        uint4 u1 = *(const uint4*)(zbf_in + (size_t)j1 * 256 + frag);
        uint4 u2 = *(const uint4*)(zbf_in + (size_t)j2 * 256 + frag);
        uint4 u3 = *(const uint4*)(zbf_in + (size_t)j3 * 256 + frag);
        edge_step(zi, acc, u0);
        edge_step(zi, acc, u1);
        edge_step(zi, acc, u2);
        edge_step(zi, acc, u3);
    }
    for (; e < end; e++) {
        int j0 = s_cols[e] & (N_NODES - 1);
        uint4 u0 = *(const uint4*)(zbf_in + (size_t)j0 * 256 + frag);
        edge_step(zi, acc, u0);
    }

    int flat = g * D_DIM + s * 8;
    if (w) {
        *(float4*)&s_acc[w - 1][flat]     = make_float4(acc[0], acc[1], acc[2], acc[3]);
        *(float4*)&s_acc[w - 1][flat + 4] = make_float4(acc[4], acc[5], acc[6], acc[7]);
    }
    __syncthreads();
    if (w == 0) {
        #pragma unroll
        for (int q = 0; q < 3; q++) {
            float4 p0 = *(const float4*)&s_acc[q][flat];
            float4 p1 = *(const float4*)&s_acc[q][flat + 4];
            acc[0] += p0.x; acc[1] += p0.y; acc[2] += p0.z; acc[3] += p0.w;
            acc[4] += p1.x; acc[5] += p1.y; acc[6] += p1.z; acc[7] += p1.w;
        }
        float ss = 0.f;
        #pragma unroll
        for (int k = 0; k < 8; k++) ss = fmaf(acc[k], acc[k], ss);
        ss = dpp_add<0xB1>(ss);
        ss = dpp_add<0x4E>(ss);
        ss = dpp_add<0x141>(ss);
        float sc = __builtin_amdgcn_rsqf(fmaxf(ss, 1e-12f));
        float o[8];
        #pragma unroll
        for (int k = 0; k < 8; k++) o[k] = acc[k] * sc;
        uintx4 ob;
        ob.x = pack2bf(o[0], o[1]); ob.y = pack2bf(o[2], o[3]);
        ob.z = pack2bf(o[4], o[5]); ob.w = pack2bf(o[6], o[7]);
        __builtin_nontemporal_store(ob, (uintx4*)(zbf_out + (size_t)i * 256 + frag));
    }
}

// ---------------------------------------------------------------------------
// Final GEMM via MFMA bf16: out[4096x128] = zbf[4096x512] @ Wo + bias.
// ---------------------------------------------------------------------------
__global__ __launch_bounds__(256) void out_gemm_mfma(
        const unsigned* __restrict__ zbf, const unsigned* __restrict__ wot_u,
        const void* __restrict__ bias, void* __restrict__ out,
        const void* __restrict__ feat) {
    bool isbf = wave_detect((const unsigned*)feat);
    int w = threadIdx.x >> 6, lane = threadIdx.x & 63;
    int r0 = blockIdx.x * 32 + (w & 1) * 16;
    int n0 = (w >> 1) * 64;
    int m = lane & 15, quad = lane >> 4;

    floatx4 acc0 = {0.f, 0.f, 0.f, 0.f}, acc1 = acc0, acc2 = acc0, acc3 = acc0;
    const unsigned* ap  = zbf   + (size_t)(r0 + m) * 256 + quad * 4;
    const unsigned* bp0 = wot_u + (size_t)(n0 + m) * 256 + quad * 4;
    const unsigned* bp1 = bp0 + 16 * 256;
    const unsigned* bp2 = bp0 + 32 * 256;
    const unsigned* bp3 = bp0 + 48 * 256;

    #pragma unroll
    for (int k0 = 0; k0 < 256; k0 += 16) {
        short8 a  = as_s8(*(const uint4*)(ap  + k0));
        short8 b0 = as_s8(*(const uint4*)(bp0 + k0));
        short8 b1 = as_s8(*(const uint4*)(bp1 + k0));
        short8 b2 = as_s8(*(const uint4*)(bp2 + k0));
        short8 b3 = as_s8(*(const uint4*)(bp3 + k0));
        acc0 = __builtin_amdgcn_mfma_f32_16x16x32_bf16(a, b0, acc0, 0, 0, 0);
        acc1 = __builtin_amdgcn_mfma_f32_16x16x32_bf16(a, b1, acc1, 0, 0, 0);
        acc2 = __builtin_amdgcn_mfma_f32_16x16x32_bf16(a, b2, acc2, 0, 0, 0);
        acc3 = __builtin_amdgcn_mfma_f32_16x16x32_bf16(a, b3, acc3, 0, 0, 0);
    }

    float accs[4][4] = {
        {acc0[0], acc0[1], acc0[2], acc0[3]},
        {acc1[0], acc1[1], acc1[2], acc1[3]},
        {acc2[0], acc2[1], acc2[2], acc2[3]},
        {acc3[0], acc3[1], acc3[2], acc3[3]}};
    #pragma unroll
    for (int c = 0; c < 4; c++) {
        int col = n0 + c * 16 + m;
        float bb = isbf ? bf2f(((const bf16*)bias)[col]) : ((const float*)bias)[col];
        #pragma unroll
        for (int r = 0; r < 4; r++) {
            int row = r0 + quad * 4 + r;
            float v = accs[c][r] + bb;
            size_t oi = (size_t)row * OUT_DIM + col;
            if (isbf) ((bf16*)out)[oi] = __float2bfloat16(v);
            else      ((float*)out)[oi] = v;
        }
    }
}

// ---------------------------------------------------------------------------
extern "C" void kernel_launch(void* const* d_in, const int* in_sizes, int n_in,
                              void* d_out, int out_size, void* d_ws, size_t ws_size,
                              hipStream_t stream) {
    const void* feat = d_in[0];
    const void* adj  = d_in[1];
    const void* W    = d_in[2];
    const void* b    = d_in[3];
    const void* Wo   = d_in[4];
    const void* bias = d_in[5];

    char* ws = (char*)d_ws;
    unsigned*       zbf_a   = (unsigned*)ws;                                // 4 MB
    unsigned*       zbf_b   = (unsigned*)(ws + (4u << 20));                 // 4 MB
    unsigned short* Wt      = (unsigned short*)(ws + (8u << 20));           // 256 KB
    unsigned short* Wo_t    = (unsigned short*)(ws + (8u << 20) + (256u << 10)); // 128 KB
    int*            deg     = (int*)(ws + (8u << 20) + (512u << 10));       // 16 KB
    int*            col_buf = (int*)(ws + (9u << 20));                      // 2 MB

    stage_a<<<72, 256, 0, stream>>>(feat, W, Wo, Wt, Wo_t);
    stage_b<<<1280, 256, 0, stream>>>(feat, adj, b, Wt, zbf_a, deg, col_buf);

    unsigned* bin = zbf_a;
    unsigned* bot = zbf_b;
    for (int it = 0; it < ITERS; it++) {
        route_kernel<<<N_NODES, 256, 0, stream>>>(bin, bot, deg, col_buf);
        unsigned* tb = bin; bin = bot; bot = tb;
    }
    // ITERS=4 even -> final state back in zbf_a
    out_gemm_mfma<<<N_NODES / 32, 256, 0, stream>>>(zbf_a, (const unsigned*)Wo_t,
                                                    bias, d_out, feat);
}

// Round 18
// 206.142 us; speedup vs baseline: 1.0138x; 1.0138x over previous
//
#include <hip/hip_runtime.h>
#include <hip/hip_bf16.h>

#define N_NODES 4096
#define C_CH    8
#define IN_DIM  256
#define D_DIM   64
#define CD      512
#define OUT_DIM 128
#define ITERS   4
#define STRIDE  128     // max degree slack (mean 41, sd 6.4; 128 is >13 sigma)

typedef __hip_bfloat16 bf16;
typedef short short8 __attribute__((ext_vector_type(8)));
typedef float floatx4 __attribute__((ext_vector_type(4)));

__device__ __forceinline__ float bf2f(bf16 x) { return __bfloat162float(x); }

__device__ __forceinline__ unsigned f2b_rne(float x) {
    unsigned u = __float_as_uint(x);
    return (u + 0x7FFFu + ((u >> 16) & 1u)) >> 16;
}
__device__ __forceinline__ unsigned pack2bf(float a, float b) {
    return f2b_rne(a) | (f2b_rne(b) << 16);
}
__device__ __forceinline__ void unpack2(unsigned v, float& a, float& b) {
    a = __uint_as_float(v << 16);
    b = __uint_as_float(v & 0xFFFF0000u);
}
__device__ __forceinline__ short8 as_s8(uint4 u) {
    union { uint4 a; short8 b; } x; x.a = u; return x.b;
}

// VALU-pipe butterfly step: x + dpp_move(x). No DS unit involvement.
// CTRL: 0xB1 = quad_perm(1,0,3,2) -> xor1 ; 0x4E = quad_perm(2,3,0,1) -> xor2
//       0x141 = row_half_mirror -> quad swap within 8 ; 0x128 = row_ror:8
template<int CTRL>
__device__ __forceinline__ float dpp_add(float x) {
    int yi = __builtin_amdgcn_update_dpp(0, __float_as_int(x), CTRL, 0xF, 0xF, true);
    return x + __int_as_float(yi);
}

// Per-wave dtype detect from first 64 dwords of features.
__device__ __forceinline__ bool wave_detect(const unsigned* __restrict__ feat_u) {
    int lane = threadIdx.x & 63;
    unsigned u = feat_u[lane];
    int e = (u >> 7) & 0xFF;
    int vote = (e >= 0x68 && e <= 0x86) ? 1 : 0;
    #pragma unroll
    for (int off = 32; off; off >>= 1) vote += __shfl_xor(vote, off);
    return vote >= 32;
}

// ---------------------------------------------------------------------------
// Stage A: blocks [0,8) -> Wt[col][k] bf16 (LDS-tiled transpose of W);
//          blocks [8,72) -> Wo_t[n][k] bf16.
// ---------------------------------------------------------------------------
__global__ __launch_bounds__(256) void stage_a(
        const void* __restrict__ feat, const void* __restrict__ W,
        const void* __restrict__ Wo,
        unsigned short* __restrict__ Wt, unsigned short* __restrict__ Wo_t) {
    bool isbf = wave_detect((const unsigned*)feat);
    int bx = blockIdx.x, t = threadIdx.x;
    if (bx < 8) {
        __shared__ __align__(16) unsigned short lt[IN_DIM * D_DIM];   // 32 KB [k][d]
        int c = bx;
        if (isbf) {
            const uint4* p = (const uint4*)((const unsigned short*)W + (size_t)c * IN_DIM * D_DIM);
            #pragma unroll
            for (int i = 0; i < 8; i++) {
                int idx = t + i * 256;
                *(uint4*)&lt[idx * 8] = p[idx];
            }
        } else {
            const float4* p = (const float4*)((const float*)W + (size_t)c * IN_DIM * D_DIM);
            #pragma unroll
            for (int i = 0; i < 16; i++) {
                int idx = t + i * 256;
                float4 f = p[idx];
                uint2 v = make_uint2(pack2bf(f.x, f.y), pack2bf(f.z, f.w));
                *(uint2*)&lt[idx * 4] = v;
            }
        }
        __syncthreads();
        uint4* wt4 = (uint4*)Wt;
        #pragma unroll
        for (int i = 0; i < 8; i++) {
            int j = t + i * 256;
            int d = j >> 5, seg = j & 31;
            int k0 = seg * 8;
            unsigned short v[8];
            #pragma unroll
            for (int k = 0; k < 8; k++) v[k] = lt[(k0 + k) * D_DIM + d];
            uint4 o;
            o.x = v[0] | ((unsigned)v[1] << 16);
            o.y = v[2] | ((unsigned)v[3] << 16);
            o.z = v[4] | ((unsigned)v[5] << 16);
            o.w = v[6] | ((unsigned)v[7] << 16);
            wt4[(c * 64 + d) * 32 + seg] = o;
        }
    } else {
        int base = (bx - 8) * 1024 + t * 4;
        #pragma unroll
        for (int q = 0; q < 4; q++) {
            int idx = base + q;
            int k = idx >> 7, n = idx & 127;
            unsigned short v;
            if (isbf) v = ((const unsigned short*)Wo)[idx];
            else      v = (unsigned short)f2b_rne(((const float*)Wo)[idx]);
            Wo_t[n * CD + k] = v;
        }
    }
}

// ---------------------------------------------------------------------------
// Stage B: blocks [0,256) -> MFMA projection (16 rows x 512 cols per block,
// wave w covers cols w*128.. = channels 2w,2w+1); blocks [256,1280) -> build.
// C/D layout: col=lane&15, row=quad*4+reg (HW-verified).
// ---------------------------------------------------------------------------
__global__ __launch_bounds__(256) void stage_b(
        const void* __restrict__ feat, const void* __restrict__ adj,
        const void* __restrict__ b, const unsigned short* __restrict__ Wt,
        unsigned* __restrict__ zbf, int* __restrict__ deg,
        int* __restrict__ col_buf) {
    bool isbf = wave_detect((const unsigned*)feat);
    int bx = blockIdx.x, t = threadIdx.x;
    int w = t >> 6, lane = t & 63;
    __shared__ __align__(16) unsigned short zt[16 * CD];   // 16 KB

    if (bx < 256) {
        int r0 = bx * 16;
        int n0 = w * 128;
        int m = lane & 15, quad = lane >> 4;
        int row = r0 + m;
        floatx4 acc[8];
        #pragma unroll
        for (int j = 0; j < 8; j++) acc[j] = (floatx4){0.f, 0.f, 0.f, 0.f};
        const uint4* wt4 = (const uint4*)Wt;

        if (isbf) {
            const uint4* a4 = (const uint4*)feat + (size_t)row * 32 + quad;
            #pragma unroll
            for (int k0 = 0; k0 < 8; k0++) {
                short8 a = as_s8(a4[k0 * 4]);
                #pragma unroll
                for (int j = 0; j < 8; j++) {
                    int col = n0 + j * 16 + m;
                    short8 bb = as_s8(wt4[col * 32 + k0 * 4 + quad]);
                    acc[j] = __builtin_amdgcn_mfma_f32_16x16x32_bf16(a, bb, acc[j], 0, 0, 0);
                }
            }
        } else {
            const float4* a4 = (const float4*)feat + (size_t)row * 64 + quad * 2;
            #pragma unroll
            for (int k0 = 0; k0 < 8; k0++) {
                float4 f0 = a4[k0 * 8], f1 = a4[k0 * 8 + 1];
                uint4 au;
                au.x = pack2bf(f0.x, f0.y); au.y = pack2bf(f0.z, f0.w);
                au.z = pack2bf(f1.x, f1.y); au.w = pack2bf(f1.z, f1.w);
                short8 a = as_s8(au);
                #pragma unroll
                for (int j = 0; j < 8; j++) {
                    int col = n0 + j * 16 + m;
                    short8 bb = as_s8(wt4[col * 32 + k0 * 4 + quad]);
                    acc[j] = __builtin_amdgcn_mfma_f32_16x16x32_bf16(a, bb, acc[j], 0, 0, 0);
                }
            }
        }

        float pre[8][4];
        #pragma unroll
        for (int j = 0; j < 8; j++) {
            int col = n0 + j * 16 + m;
            float bb = isbf ? bf2f(((const bf16*)b)[col]) : ((const float*)b)[col];
            #pragma unroll
            for (int r = 0; r < 4; r++) pre[j][r] = acc[j][r] + bb;
        }
        #pragma unroll
        for (int ch = 0; ch < 2; ch++) {
            float ss[4];
            #pragma unroll
            for (int r = 0; r < 4; r++) {
                float s = 0.f;
                #pragma unroll
                for (int jj = 0; jj < 4; jj++) {
                    float v = pre[ch * 4 + jj][r];
                    s = fmaf(v, v, s);
                }
                ss[r] = s;
            }
            #pragma unroll
            for (int off = 1; off < 16; off <<= 1) {
                #pragma unroll
                for (int r = 0; r < 4; r++) ss[r] += __shfl_xor(ss[r], off);
            }
            #pragma unroll
            for (int r = 0; r < 4; r++) {
                float sc = __builtin_amdgcn_rsqf(fmaxf(ss[r], 1e-12f));
                int lrow = quad * 4 + r;
                #pragma unroll
                for (int jj = 0; jj < 4; jj++) {
                    int j = ch * 4 + jj;
                    int col = n0 + j * 16 + m;
                    zt[lrow * CD + col] = (unsigned short)f2b_rne(pre[j][r] * sc);
                }
            }
        }
        __syncthreads();
        const uint4* zt4 = (const uint4*)zt;
        uint4* z4 = (uint4*)zbf;
        #pragma unroll
        for (int i = 0; i < 4; i++) {
            int j = t + i * 256;
            int lrow = j >> 6, seg = j & 63;
            z4[(size_t)(r0 + lrow) * 64 + seg] = zt4[j];
        }
    } else {
        // ----- build: one wave per adjacency row, shfl scan
        int i = (bx - 256) * 4 + w;
        int base_out = i * STRIDE;
        int running = 0;
        int nch = isbf ? 8 : 16;
        for (int ch = 0; ch < nch; ch++) {
            unsigned bits = 0;
            int j0, nelem;
            if (isbf) {
                const uint4* p = (const uint4*)((const unsigned short*)adj + (size_t)i * N_NODES);
                uint4 u = p[ch * 64 + lane];
                j0 = (ch * 64 + lane) * 8; nelem = 8;
                unsigned short h[8] = {
                    (unsigned short)(u.x & 0xFFFF), (unsigned short)(u.x >> 16),
                    (unsigned short)(u.y & 0xFFFF), (unsigned short)(u.y >> 16),
                    (unsigned short)(u.z & 0xFFFF), (unsigned short)(u.z >> 16),
                    (unsigned short)(u.w & 0xFFFF), (unsigned short)(u.w >> 16)};
                #pragma unroll
                for (int k = 0; k < 8; k++)
                    if ((h[k] & 0x8000) == 0 && h[k] != 0) bits |= (1u << k);
            } else {
                const float4* p = (const float4*)((const float*)adj + (size_t)i * N_NODES);
                float4 f = p[ch * 64 + lane];
                j0 = (ch * 64 + lane) * 4; nelem = 4;
                if (f.x > 0.f) bits |= 1u;
                if (f.y > 0.f) bits |= 2u;
                if (f.z > 0.f) bits |= 4u;
                if (f.w > 0.f) bits |= 8u;
            }
            int cnt = __popc(bits);
            int sc = cnt;
            #pragma unroll
            for (int off = 1; off < 64; off <<= 1) {
                int v = __shfl_up(sc, off);
                if (lane >= off) sc += v;
            }
            int tot = __shfl(sc, 63);
            int pos = base_out + running + (sc - cnt);
            for (int k = 0; k < nelem; k++) {
                if ((bits >> k) & 1u) {
                    if (pos < base_out + STRIDE) col_buf[pos] = j0 + k;
                    pos++;
                }
            }
            running += tot;
        }
        if (lane == 0) deg[i] = (running < STRIDE) ? running : STRIDE;
    }
}

// ---------------------------------------------------------------------------
// Routing iteration: ONE node per block, edge list split across 4 waves,
// partials combined in LDS. Per-edge dot reduce on VALU DPP (3 adds);
// softmax channel sum: row_ror:8 DPP + shfl_xor 16/32. (R15 config — best.)
// Lane: g = lane>>3 (channel), s = lane&7 (dim octet).
// ---------------------------------------------------------------------------
__device__ __forceinline__ void edge_step(const float zi[8], float acc[8], uint4 u) {
    float vj[8];
    unpack2(u.x, vj[0], vj[1]);
    unpack2(u.y, vj[2], vj[3]);
    unpack2(u.z, vj[4], vj[5]);
    unpack2(u.w, vj[6], vj[7]);
    float p = 0.f;
    #pragma unroll
    for (int k = 0; k < 8; k++) p = fmaf(zi[k], vj[k], p);
    // reduce over s (8 lanes) entirely on the VALU pipe
    p = dpp_add<0xB1>(p);      // xor1
    p = dpp_add<0x4E>(p);      // xor2
    p = dpp_add<0x141>(p);     // quad swap within 8
    float ex = __expf(p);      // |p| <= 1 (unit vectors): shift-free softmax
    // channel sum: stride 8 on DPP; strides 16/32 via DS shuffle
    float s = dpp_add<0x128>(ex);       // row_ror:8
    s += __shfl_xor(s, 16);
    s += __shfl_xor(s, 32);
    float wgt = ex * __builtin_amdgcn_rcpf(s);
    #pragma unroll
    for (int k = 0; k < 8; k++) acc[k] = fmaf(wgt, vj[k], acc[k]);
}

__global__ __launch_bounds__(256) void route_kernel(
        const unsigned* __restrict__ zbf_in, unsigned* __restrict__ zbf_out,
        const int* __restrict__ deg, const int* __restrict__ col_buf) {
    int t = threadIdx.x;
    int w = t >> 6, lane = t & 63;
    int i = blockIdx.x;
    int g = lane >> 3, s = lane & 7;
    __shared__ int   s_cols[STRIDE];
    __shared__ float s_acc[3][CD];
    if (t < STRIDE) s_cols[t] = col_buf[i * STRIDE + t];
    __syncthreads();

    int frag = g * 32 + s * 4;
    uint4 uown = *(const uint4*)(zbf_in + (size_t)i * 256 + frag);
    float zi[8], acc[8];
    unpack2(uown.x, zi[0], zi[1]); unpack2(uown.y, zi[2], zi[3]);
    unpack2(uown.z, zi[4], zi[5]); unpack2(uown.w, zi[6], zi[7]);
    #pragma unroll
    for (int k = 0; k < 8; k++) acc[k] = (w == 0) ? zi[k] : 0.f;  // residual once

    int dg = deg[i];
    int e   = (dg * w) >> 2;
    int end = (dg * (w + 1)) >> 2;
    for (; e + 3 < end; e += 4) {
        int j0 = s_cols[e]     & (N_NODES - 1);
        int j1 = s_cols[e + 1] & (N_NODES - 1);
        int j2 = s_cols[e + 2] & (N_NODES - 1);
        int j3 = s_cols[e + 3] & (N_NODES - 1);
        uint4 u0 = *(const uint4*)(zbf_in + (size_t)j0 * 256 + frag);
        uint4 u1 = *(const uint4*)(zbf_in + (size_t)j1 * 256 + frag);
        uint4 u2 = *(const uint4*)(zbf_in + (size_t)j2 * 256 + frag);
        uint4 u3 = *(const uint4*)(zbf_in + (size_t)j3 * 256 + frag);
        edge_step(zi, acc, u0);
        edge_step(zi, acc, u1);
        edge_step(zi, acc, u2);
        edge_step(zi, acc, u3);
    }
    for (; e < end; e++) {
        int j0 = s_cols[e] & (N_NODES - 1);
        uint4 u0 = *(const uint4*)(zbf_in + (size_t)j0 * 256 + frag);
        edge_step(zi, acc, u0);
    }

    int flat = g * D_DIM + s * 8;
    if (w) {
        *(float4*)&s_acc[w - 1][flat]     = make_float4(acc[0], acc[1], acc[2], acc[3]);
        *(float4*)&s_acc[w - 1][flat + 4] = make_float4(acc[4], acc[5], acc[6], acc[7]);
    }
    __syncthreads();
    if (w == 0) {
        #pragma unroll
        for (int q = 0; q < 3; q++) {
            float4 p0 = *(const float4*)&s_acc[q][flat];
            float4 p1 = *(const float4*)&s_acc[q][flat + 4];
            acc[0] += p0.x; acc[1] += p0.y; acc[2] += p0.z; acc[3] += p0.w;
            acc[4] += p1.x; acc[5] += p1.y; acc[6] += p1.z; acc[7] += p1.w;
        }
        float ss = 0.f;
        #pragma unroll
        for (int k = 0; k < 8; k++) ss = fmaf(acc[k], acc[k], ss);
        ss = dpp_add<0xB1>(ss);
        ss = dpp_add<0x4E>(ss);
        ss = dpp_add<0x141>(ss);
        float sc = __builtin_amdgcn_rsqf(fmaxf(ss, 1e-12f));
        float o[8];
        #pragma unroll
        for (int k = 0; k < 8; k++) o[k] = acc[k] * sc;
        uint4 ob;
        ob.x = pack2bf(o[0], o[1]); ob.y = pack2bf(o[2], o[3]);
        ob.z = pack2bf(o[4], o[5]); ob.w = pack2bf(o[6], o[7]);
        *(uint4*)(zbf_out + (size_t)i * 256 + frag) = ob;
    }
}

// ---------------------------------------------------------------------------
// Final GEMM via MFMA bf16: out[4096x128] = zbf[4096x512] @ Wo + bias.
// ---------------------------------------------------------------------------
__global__ __launch_bounds__(256) void out_gemm_mfma(
        const unsigned* __restrict__ zbf, const unsigned* __restrict__ wot_u,
        const void* __restrict__ bias, void* __restrict__ out,
        const void* __restrict__ feat) {
    bool isbf = wave_detect((const unsigned*)feat);
    int w = threadIdx.x >> 6, lane = threadIdx.x & 63;
    int r0 = blockIdx.x * 32 + (w & 1) * 16;
    int n0 = (w >> 1) * 64;
    int m = lane & 15, quad = lane >> 4;

    floatx4 acc0 = {0.f, 0.f, 0.f, 0.f}, acc1 = acc0, acc2 = acc0, acc3 = acc0;
    const unsigned* ap  = zbf   + (size_t)(r0 + m) * 256 + quad * 4;
    const unsigned* bp0 = wot_u + (size_t)(n0 + m) * 256 + quad * 4;
    const unsigned* bp1 = bp0 + 16 * 256;
    const unsigned* bp2 = bp0 + 32 * 256;
    const unsigned* bp3 = bp0 + 48 * 256;

    #pragma unroll
    for (int k0 = 0; k0 < 256; k0 += 16) {
        short8 a  = as_s8(*(const uint4*)(ap  + k0));
        short8 b0 = as_s8(*(const uint4*)(bp0 + k0));
        short8 b1 = as_s8(*(const uint4*)(bp1 + k0));
        short8 b2 = as_s8(*(const uint4*)(bp2 + k0));
        short8 b3 = as_s8(*(const uint4*)(bp3 + k0));
        acc0 = __builtin_amdgcn_mfma_f32_16x16x32_bf16(a, b0, acc0, 0, 0, 0);
        acc1 = __builtin_amdgcn_mfma_f32_16x16x32_bf16(a, b1, acc1, 0, 0, 0);
        acc2 = __builtin_amdgcn_mfma_f32_16x16x32_bf16(a, b2, acc2, 0, 0, 0);
        acc3 = __builtin_amdgcn_mfma_f32_16x16x32_bf16(a, b3, acc3, 0, 0, 0);
    }

    float accs[4][4] = {
        {acc0[0], acc0[1], acc0[2], acc0[3]},
        {acc1[0], acc1[1], acc1[2], acc1[3]},
        {acc2[0], acc2[1], acc2[2], acc2[3]},
        {acc3[0], acc3[1], acc3[2], acc3[3]}};
    #pragma unroll
    for (int c = 0; c < 4; c++) {
        int col = n0 + c * 16 + m;
        float bb = isbf ? bf2f(((const bf16*)bias)[col]) : ((const float*)bias)[col];
        #pragma unroll
        for (int r = 0; r < 4; r++) {
            int row = r0 + quad * 4 + r;
            float v = accs[c][r] + bb;
            size_t oi = (size_t)row * OUT_DIM + col;
            if (isbf) ((bf16*)out)[oi] = __float2bfloat16(v);
            else      ((float*)out)[oi] = v;
        }
    }
}

// ---------------------------------------------------------------------------
extern "C" void kernel_launch(void* const* d_in, const int* in_sizes, int n_in,
                              void* d_out, int out_size, void* d_ws, size_t ws_size,
                              hipStream_t stream) {
    const void* feat = d_in[0];
    const void* adj  = d_in[1];
    const void* W    = d_in[2];
    const void* b    = d_in[3];
    const void* Wo   = d_in[4];
    const void* bias = d_in[5];

    char* ws = (char*)d_ws;
    unsigned*       zbf_a   = (unsigned*)ws;                                // 4 MB
    unsigned*       zbf_b   = (unsigned*)(ws + (4u << 20));                 // 4 MB
    unsigned short* Wt      = (unsigned short*)(ws + (8u << 20));           // 256 KB
    unsigned short* Wo_t    = (unsigned short*)(ws + (8u << 20) + (256u << 10)); // 128 KB
    int*            deg     = (int*)(ws + (8u << 20) + (512u << 10));       // 16 KB
    int*            col_buf = (int*)(ws + (9u << 20));                      // 2 MB

    stage_a<<<72, 256, 0, stream>>>(feat, W, Wo, Wt, Wo_t);
    stage_b<<<1280, 256, 0, stream>>>(feat, adj, b, Wt, zbf_a, deg, col_buf);

    unsigned* bin = zbf_a;
    unsigned* bot = zbf_b;
    for (int it = 0; it < ITERS; it++) {
        route_kernel<<<N_NODES, 256, 0, stream>>>(bin, bot, deg, col_buf);
        unsigned* tb = bin; bin = bot; bot = tb;
    }
    // ITERS=4 even -> final state back in zbf_a
    out_gemm_mfma<<<N_NODES / 32, 256, 0, stream>>>(zbf_a, (const unsigned*)Wo_t,
                                                    bias, d_out, feat);
}